// Round 1
// baseline (1644.896 us; speedup 1.0000x reference)
//
#include <hip/hip_runtime.h>
#include <math.h>

#define BATCH  8192
#define DIM    128
#define NTREES 512
#define DEPTH  6
#define UNITS  8
#define NLEAF  64

#define ROWS_PER_BLOCK 64
#define TREES_PER_SUB  8
#define SUBTILES       4
#define TREES_PER_BLOCK (TREES_PER_SUB*SUBTILES)   // 32
#define TREE_BLOCKS     (NTREES/TREES_PER_BLOCK)   // 16
#define TPB 128

#define INP_STRIDE 132   // 128 + 4 pad -> rows land on rotating banks
#define SEL_STRIDE 772   // 6*128 + 4 pad (mult of 4 for float4 alignment)
#define R_STRIDE   520   // 8*64 + 8 pad

// ---------------------------------------------------------------------------
// Kernel 1: sparsemax over the dim axis for each (tree, depth) row, fused with
// the temperature scaling.  selScaled[n][d][i] = sparsemax(z)[i] * exp(-logT),
// bias[n][d] = -threshold * exp(-logT).
// Sort-free sparsemax: elem i is in support iff 1 + k_i*z_i > S_i where
// k_i = #{j : z_j >= z_i}, S_i = sum_{z_j >= z_i} z_j.  (Exactly matches the
// sorted prefix test, including ties.)
// ---------------------------------------------------------------------------
__global__ __launch_bounds__(DIM) void sparsemax_prep(
    const float* __restrict__ logits, const float* __restrict__ thr,
    const float* __restrict__ logtemp, float* __restrict__ selScaled,
    float* __restrict__ bias)
{
  int rd = blockIdx.x;                 // rd = n*DEPTH + d
  int n = rd / DEPTH, d = rd - n*DEPTH;
  int i = threadIdx.x;
  __shared__ float z[DIM];
  __shared__ float redc[DIM], reds[DIM];

  // logits layout: (dim, n_trees, depth)
  float zi = logits[((size_t)i*NTREES + n)*DEPTH + d];
  z[i] = zi;
  __syncthreads();

  float k = 0.f, S = 0.f;
  for (int j = 0; j < DIM; ++j) {
    float zj = z[j];
    if (zj >= zi) { k += 1.f; S += zj; }
  }
  bool sup = (1.f + k*zi) > S;
  redc[i] = sup ? 1.f : 0.f;
  reds[i] = sup ? zi  : 0.f;
  __syncthreads();
  for (int off = 64; off > 0; off >>= 1) {
    if (i < off) { redc[i] += redc[i+off]; reds[i] += reds[i+off]; }
    __syncthreads();
  }
  float kz = redc[0], sumTop = reds[0];
  float tau = (sumTop - 1.f) / kz;
  float et  = expf(-logtemp[rd]);
  selScaled[(size_t)rd*DIM + i] = fmaxf(zi - tau, 0.f) * et;
  if (i == 0) bias[rd] = -thr[rd]*et;
}

// ---------------------------------------------------------------------------
// Kernel 2: fused  fv-GEMM -> gates -> leaf products -> response contraction.
// Block: 128 threads = 8 trees (tx) x 16 ty; each thread owns 4 batch rows
// (row = ty + 16k) and one tree per subtile; 4 subtiles of 8 trees -> 32
// trees/block.  Partial sums per tree-block written to ws, reduced later.
// ---------------------------------------------------------------------------
__global__ __launch_bounds__(TPB) void odt_main(
    const float* __restrict__ inputs, const float* __restrict__ selScaled,
    const float* __restrict__ bias, const float* __restrict__ response,
    float* __restrict__ partial)
{
  __shared__ float inp_lds[ROWS_PER_BLOCK * INP_STRIDE];   // 33792 B
  __shared__ float sel_lds[TREES_PER_SUB * SEL_STRIDE];    // 24704 B
  __shared__ float r_lds[TREES_PER_SUB * R_STRIDE];        // 16640 B
  __shared__ float bias_lds[TREES_PER_SUB * DEPTH];        // 192 B

  const int tid = threadIdx.x;
  const int tx = tid & 7;    // tree within subtile
  const int ty = tid >> 3;   // 0..15
  const int rowBase   = blockIdx.x * ROWS_PER_BLOCK;
  const int treeBase0 = blockIdx.y * TREES_PER_BLOCK;

  // stage the 64x128 input tile once (coalesced float4)
  {
    const float4* in4 = (const float4*)(inputs + (size_t)rowBase*DIM);
    for (int idx = tid; idx < ROWS_PER_BLOCK*DIM/4; idx += TPB) {
      int r  = idx >> 5;       // /(DIM/4)
      int c4 = idx & 31;
      float4 v = in4[idx];
      float* dst = &inp_lds[r*INP_STRIDE + c4*4];
      dst[0]=v.x; dst[1]=v.y; dst[2]=v.z; dst[3]=v.w;
    }
  }

  float acc[4][UNITS];
  #pragma unroll
  for (int k = 0; k < 4; ++k)
    #pragma unroll
    for (int u = 0; u < UNITS; ++u) acc[k][u] = 0.f;

  for (int st = 0; st < SUBTILES; ++st) {
    const int treeBase = treeBase0 + st*TREES_PER_SUB;
    __syncthreads();   // previous subtile's readers are done
    // stage sel (8 trees x 768 floats) and response (8 trees x 512 floats)
    {
      const float4* s4 = (const float4*)(selScaled + (size_t)treeBase*DEPTH*DIM);
      for (int idx = tid; idx < TREES_PER_SUB*DEPTH*DIM/4; idx += TPB) { // 1536
        int t = idx / 192, rem = idx - t*192;
        float4 v = s4[idx];
        float* dst = &sel_lds[t*SEL_STRIDE + rem*4];
        dst[0]=v.x; dst[1]=v.y; dst[2]=v.z; dst[3]=v.w;
      }
      const float4* r4 = (const float4*)(response + (size_t)treeBase*UNITS*NLEAF);
      for (int idx = tid; idx < TREES_PER_SUB*UNITS*NLEAF/4; idx += TPB) { // 1024
        int t = idx >> 7, rem = idx & 127;
        float4 v = r4[idx];
        float* dst = &r_lds[t*R_STRIDE + rem*4];
        dst[0]=v.x; dst[1]=v.y; dst[2]=v.z; dst[3]=v.w;
      }
      if (tid < TREES_PER_SUB*DEPTH) bias_lds[tid] = bias[treeBase*DEPTH + tid];
    }
    __syncthreads();

    // fv[k][d] = dot(input_row_k, selScaled[tree][d])
    float fv[4][DEPTH];
    #pragma unroll
    for (int k = 0; k < 4; ++k)
      #pragma unroll
      for (int d = 0; d < DEPTH; ++d) fv[k][d] = 0.f;

    const float* selp = &sel_lds[tx*SEL_STRIDE];
    #pragma unroll 4
    for (int i4 = 0; i4 < DIM/4; ++i4) {
      float4 a[4];
      #pragma unroll
      for (int k = 0; k < 4; ++k)
        a[k] = *(const float4*)&inp_lds[(ty + 16*k)*INP_STRIDE + i4*4];
      #pragma unroll
      for (int d = 0; d < DEPTH; ++d) {
        float4 b = *(const float4*)&selp[d*DIM + i4*4];
        #pragma unroll
        for (int k = 0; k < 4; ++k)
          fv[k][d] += a[k].x*b.x + a[k].y*b.y + a[k].z*b.z + a[k].w*b.w;
      }
    }

    // epilogue: gates -> leaf probabilities -> response
    const float4* rp4 = (const float4*)&r_lds[tx*R_STRIDE];
    #pragma unroll
    for (int k = 0; k < 4; ++k) {
      float s[DEPTH], om[DEPTH];
      #pragma unroll
      for (int d = 0; d < DEPTH; ++d) {
        float tl = fv[k][d] + bias_lds[tx*DEPTH + d];
        float sv = fminf(fmaxf(0.5f + 0.5f*tl, 0.f), 1.f);  // gate for bit=0
        s[d] = sv; om[d] = 1.f - sv;                        // gate for bit=1
      }
      // progressive tensor product: p[c] = prod_d (bit_d(c) ? om[d] : s[d])
      float p[NLEAF];
      p[0] = 1.f;
      #pragma unroll
      for (int d = 0; d < DEPTH; ++d) {
        const int sz = 1 << d;
        float sv = s[d], ov = om[d];
        #pragma unroll
        for (int c = 0; c < (1 << d); ++c) {
          float v = p[c];
          p[c + sz] = v * ov;
          p[c]      = v * sv;
        }
      }
      #pragma unroll
      for (int u = 0; u < UNITS; ++u) {
        float sum = 0.f;
        #pragma unroll
        for (int c4 = 0; c4 < NLEAF/4; ++c4) {
          float4 rv = rp4[u*(NLEAF/4) + c4];
          sum += p[c4*4+0]*rv.x + p[c4*4+1]*rv.y
               + p[c4*4+2]*rv.z + p[c4*4+3]*rv.w;
        }
        acc[k][u] += sum;
      }
    }
  }

  // reduce across the 8 trees (tx = low 3 lane bits) via shuffles
  #pragma unroll
  for (int k = 0; k < 4; ++k)
    #pragma unroll
    for (int u = 0; u < UNITS; ++u) {
      float v = acc[k][u];
      v += __shfl_xor(v, 1);
      v += __shfl_xor(v, 2);
      v += __shfl_xor(v, 4);
      acc[k][u] = v;
    }
  if (tx == 0) {
    #pragma unroll
    for (int k = 0; k < 4; ++k) {
      int row = rowBase + ty + 16*k;
      float* dst = &partial[((size_t)blockIdx.y * BATCH + row)*UNITS];
      #pragma unroll
      for (int u = 0; u < UNITS; ++u) dst[u] = acc[k][u];
    }
  }
}

// ---------------------------------------------------------------------------
// Kernel 3: sum the 16 tree-block partials, scale by 1/512.
// ---------------------------------------------------------------------------
__global__ __launch_bounds__(256) void odt_reduce(
    const float* __restrict__ partial, float* __restrict__ out)
{
  int i = blockIdx.x*256 + threadIdx.x;   // 0..65535
  float s = 0.f;
  #pragma unroll
  for (int tb = 0; tb < TREE_BLOCKS; ++tb)
    s += partial[(size_t)tb*BATCH*UNITS + i];
  out[i] = s * (1.f/NTREES);
}

extern "C" void kernel_launch(void* const* d_in, const int* in_sizes, int n_in,
                              void* d_out, int out_size, void* d_ws, size_t ws_size,
                              hipStream_t stream)
{
  const float* inputs   = (const float*)d_in[0];
  const float* logits   = (const float*)d_in[1];
  const float* thr      = (const float*)d_in[2];
  const float* logtemp  = (const float*)d_in[3];
  const float* response = (const float*)d_in[4];
  float* out = (float*)d_out;

  float* ws        = (float*)d_ws;
  float* selScaled = ws;                          // 512*6*128 = 393216 floats
  float* bias      = selScaled + NTREES*DEPTH*DIM;// 3072 floats
  float* partial   = bias + NTREES*DEPTH;         // 16*8192*8 = 1048576 floats

  hipLaunchKernelGGL(sparsemax_prep, dim3(NTREES*DEPTH), dim3(DIM), 0, stream,
                     logits, thr, logtemp, selScaled, bias);
  hipLaunchKernelGGL(odt_main,
                     dim3(BATCH/ROWS_PER_BLOCK, TREE_BLOCKS), dim3(TPB), 0, stream,
                     inputs, selScaled, bias, response, partial);
  hipLaunchKernelGGL(odt_reduce, dim3(BATCH*UNITS/256), dim3(256), 0, stream,
                     partial, out);
}

// Round 2
// 659.146 us; speedup vs baseline: 2.4955x; 2.4955x over previous
//
#include <hip/hip_runtime.h>
#include <math.h>

#define BATCH  8192
#define DIM    128
#define NTREES 512
#define DEPTH  6
#define UNITS  8
#define NLEAF  64

#define ROWS_PER_BLOCK 64
#define KROWS 2
#define TREES_PER_SUB  8
#define SUBTILES       4
#define TREES_PER_BLOCK (TREES_PER_SUB*SUBTILES)   // 32
#define TREE_BLOCKS     (NTREES/TREES_PER_BLOCK)   // 16
#define TPB 256

#define INP_STRIDE 132   // 128 + 4 pad -> 8 row-addrs spread across all 32 banks
#define SEL_STRIDE 772   // 768 + 4 pad
#define R_STRIDE   520   // 512 + 8 pad

// ---------------------------------------------------------------------------
// Kernel 1: sort-free sparsemax per (tree,depth) row over dim, fused with
// temperature: selScaled = sparsemax(z)*exp(-logT), bias = -thr*exp(-logT).
// ---------------------------------------------------------------------------
__global__ __launch_bounds__(DIM) void sparsemax_prep(
    const float* __restrict__ logits, const float* __restrict__ thr,
    const float* __restrict__ logtemp, float* __restrict__ selScaled,
    float* __restrict__ bias)
{
  int rd = blockIdx.x;                 // rd = n*DEPTH + d
  int n = rd / DEPTH, d = rd - n*DEPTH;
  int i = threadIdx.x;
  __shared__ float z[DIM];
  __shared__ float redc[DIM], reds[DIM];

  float zi = logits[((size_t)i*NTREES + n)*DEPTH + d];
  z[i] = zi;
  __syncthreads();

  float k = 0.f, S = 0.f;
  for (int j = 0; j < DIM; ++j) {
    float zj = z[j];
    if (zj >= zi) { k += 1.f; S += zj; }
  }
  bool sup = (1.f + k*zi) > S;
  redc[i] = sup ? 1.f : 0.f;
  reds[i] = sup ? zi  : 0.f;
  __syncthreads();
  for (int off = 64; off > 0; off >>= 1) {
    if (i < off) { redc[i] += redc[i+off]; reds[i] += reds[i+off]; }
    __syncthreads();
  }
  float kz = redc[0], sumTop = reds[0];
  float tau = (sumTop - 1.f) / kz;
  float et  = expf(-logtemp[rd]);
  selScaled[(size_t)rd*DIM + i] = fmaxf(zi - tau, 0.f) * et;
  if (i == 0) bias[rd] = -thr[rd]*et;
}

// ---------------------------------------------------------------------------
// Kernel 2: fused fv-GEMM -> gates -> leaf products -> response contraction.
// 256 threads = 8 trees (tx) x 32 (ty); each thread owns 2 batch rows
// (ty, ty+32).  Leaf product kept as p5[32] (depth 0..4); the depth-5 gate is
// folded into the response contraction (saves 32 live VGPRs -> no spill).
// ---------------------------------------------------------------------------
__global__ __launch_bounds__(TPB, 4) void odt_main(
    const float* __restrict__ inputs, const float* __restrict__ selScaled,
    const float* __restrict__ bias, const float* __restrict__ response,
    float* __restrict__ partial)
{
  __shared__ float inp_lds[ROWS_PER_BLOCK * INP_STRIDE];   // 33792 B
  __shared__ float sel_lds[TREES_PER_SUB * SEL_STRIDE];    // 24704 B
  __shared__ float r_lds[TREES_PER_SUB * R_STRIDE];        // 16640 B
  __shared__ float bias_lds[TREES_PER_SUB * DEPTH];        // 192 B

  const int tid = threadIdx.x;
  const int tx = tid & 7;    // tree within subtile
  const int ty = tid >> 3;   // 0..31
  const int rowBase   = blockIdx.x * ROWS_PER_BLOCK;
  const int treeBase0 = blockIdx.y * TREES_PER_BLOCK;

  // stage the 64x128 input tile once (coalesced float4)
  {
    const float4* in4 = (const float4*)(inputs + (size_t)rowBase*DIM);
    #pragma unroll
    for (int it = 0; it < ROWS_PER_BLOCK*DIM/4/TPB; ++it) {   // 8
      int idx = tid + it*TPB;
      int r  = idx >> 5;
      int c4 = idx & 31;
      float4 v = in4[idx];
      float* dst = &inp_lds[r*INP_STRIDE + c4*4];
      dst[0]=v.x; dst[1]=v.y; dst[2]=v.z; dst[3]=v.w;
    }
  }

  float acc[KROWS][UNITS];
  #pragma unroll
  for (int k = 0; k < KROWS; ++k)
    #pragma unroll
    for (int u = 0; u < UNITS; ++u) acc[k][u] = 0.f;

  for (int st = 0; st < SUBTILES; ++st) {
    const int treeBase = treeBase0 + st*TREES_PER_SUB;
    __syncthreads();   // previous subtile's readers done
    {
      const float4* s4 = (const float4*)(selScaled + (size_t)treeBase*DEPTH*DIM);
      #pragma unroll
      for (int it = 0; it < TREES_PER_SUB*DEPTH*DIM/4/TPB; ++it) {  // 6
        int idx = tid + it*TPB;
        int t = idx / 192, rem = idx - t*192;
        float4 v = s4[idx];
        float* dst = &sel_lds[t*SEL_STRIDE + rem*4];
        dst[0]=v.x; dst[1]=v.y; dst[2]=v.z; dst[3]=v.w;
      }
      const float4* r4 = (const float4*)(response + (size_t)treeBase*UNITS*NLEAF);
      #pragma unroll
      for (int it = 0; it < TREES_PER_SUB*UNITS*NLEAF/4/TPB; ++it) { // 4
        int idx = tid + it*TPB;
        int t = idx >> 7, rem = idx & 127;
        float4 v = r4[idx];
        float* dst = &r_lds[t*R_STRIDE + rem*4];
        dst[0]=v.x; dst[1]=v.y; dst[2]=v.z; dst[3]=v.w;
      }
      if (tid < TREES_PER_SUB*DEPTH) bias_lds[tid] = bias[treeBase*DEPTH + tid];
    }
    __syncthreads();

    // fv[k][d] = dot(input_row_k, selScaled[tree][d])
    float fv[KROWS][DEPTH];
    #pragma unroll
    for (int k = 0; k < KROWS; ++k)
      #pragma unroll
      for (int d = 0; d < DEPTH; ++d) fv[k][d] = 0.f;

    const float* selp = &sel_lds[tx*SEL_STRIDE];
    const float* ap0  = &inp_lds[ty*INP_STRIDE];
    const float* ap1  = &inp_lds[(ty+32)*INP_STRIDE];
    #pragma unroll 8
    for (int i4 = 0; i4 < DIM/4; ++i4) {
      float4 a0 = *(const float4*)&ap0[i4*4];
      float4 a1 = *(const float4*)&ap1[i4*4];
      #pragma unroll
      for (int d = 0; d < DEPTH; ++d) {
        float4 b = *(const float4*)&selp[d*DIM + i4*4];
        fv[0][d] += a0.x*b.x + a0.y*b.y + a0.z*b.z + a0.w*b.w;
        fv[1][d] += a1.x*b.x + a1.y*b.y + a1.z*b.z + a1.w*b.w;
      }
    }

    // epilogue: gates -> 32-leaf product (depth 0..4) -> response with the
    // depth-5 gate folded in:  out = s5*dot(p5,R[0:32]) + o5*dot(p5,R[32:64])
    const float4* rp4 = (const float4*)&r_lds[tx*R_STRIDE];
    #pragma unroll
    for (int k = 0; k < KROWS; ++k) {
      float s[DEPTH], om[DEPTH];
      #pragma unroll
      for (int d = 0; d < DEPTH; ++d) {
        float tl = fv[k][d] + bias_lds[tx*DEPTH + d];
        float sv = fminf(fmaxf(0.5f + 0.5f*tl, 0.f), 1.f);
        s[d] = sv; om[d] = 1.f - sv;
      }
      float p5[NLEAF/2];
      p5[0] = 1.f;
      #pragma unroll
      for (int d = 0; d < DEPTH-1; ++d) {
        const int sz = 1 << d;
        float sv = s[d], ov = om[d];
        #pragma unroll
        for (int c = 0; c < (1 << d); ++c) {
          float v = p5[c];
          p5[c + sz] = v * ov;
          p5[c]      = v * sv;
        }
      }
      float s5 = s[DEPTH-1], o5 = om[DEPTH-1];
      #pragma unroll
      for (int u = 0; u < UNITS; ++u) {
        float sum0 = 0.f, sum1 = 0.f;
        #pragma unroll
        for (int c4 = 0; c4 < 8; ++c4) {
          float4 r0 = rp4[u*(NLEAF/4) + c4];       // leaves 0..31
          float4 r1 = rp4[u*(NLEAF/4) + 8 + c4];   // leaves 32..63
          sum0 += p5[c4*4+0]*r0.x + p5[c4*4+1]*r0.y
                + p5[c4*4+2]*r0.z + p5[c4*4+3]*r0.w;
          sum1 += p5[c4*4+0]*r1.x + p5[c4*4+1]*r1.y
                + p5[c4*4+2]*r1.z + p5[c4*4+3]*r1.w;
        }
        acc[k][u] += s5*sum0 + o5*sum1;
      }
    }
  }

  // reduce across the 8 trees (tx = low 3 lane bits) via shuffles
  #pragma unroll
  for (int k = 0; k < KROWS; ++k)
    #pragma unroll
    for (int u = 0; u < UNITS; ++u) {
      float v = acc[k][u];
      v += __shfl_xor(v, 1);
      v += __shfl_xor(v, 2);
      v += __shfl_xor(v, 4);
      acc[k][u] = v;
    }
  if (tx == 0) {
    #pragma unroll
    for (int k = 0; k < KROWS; ++k) {
      int row = rowBase + ty + 32*k;
      float* dst = &partial[((size_t)blockIdx.y * BATCH + row)*UNITS];
      #pragma unroll
      for (int u = 0; u < UNITS; ++u) dst[u] = acc[k][u];
    }
  }
}

// ---------------------------------------------------------------------------
// Kernel 3: sum the 16 tree-block partials, scale by 1/512.
// ---------------------------------------------------------------------------
__global__ __launch_bounds__(256) void odt_reduce(
    const float* __restrict__ partial, float* __restrict__ out)
{
  int i = blockIdx.x*256 + threadIdx.x;   // 0..65535
  float s = 0.f;
  #pragma unroll
  for (int tb = 0; tb < TREE_BLOCKS; ++tb)
    s += partial[(size_t)tb*BATCH*UNITS + i];
  out[i] = s * (1.f/NTREES);
}

extern "C" void kernel_launch(void* const* d_in, const int* in_sizes, int n_in,
                              void* d_out, int out_size, void* d_ws, size_t ws_size,
                              hipStream_t stream)
{
  const float* inputs   = (const float*)d_in[0];
  const float* logits   = (const float*)d_in[1];
  const float* thr      = (const float*)d_in[2];
  const float* logtemp  = (const float*)d_in[3];
  const float* response = (const float*)d_in[4];
  float* out = (float*)d_out;

  float* ws        = (float*)d_ws;
  float* selScaled = ws;                          // 512*6*128 = 393216 floats
  float* bias      = selScaled + NTREES*DEPTH*DIM;// 3072 floats
  float* partial   = bias + NTREES*DEPTH;         // 16*8192*8 = 1048576 floats

  hipLaunchKernelGGL(sparsemax_prep, dim3(NTREES*DEPTH), dim3(DIM), 0, stream,
                     logits, thr, logtemp, selScaled, bias);
  hipLaunchKernelGGL(odt_main,
                     dim3(BATCH/ROWS_PER_BLOCK, TREE_BLOCKS), dim3(TPB), 0, stream,
                     inputs, selScaled, bias, response, partial);
  hipLaunchKernelGGL(odt_reduce, dim3(BATCH*UNITS/256), dim3(256), 0, stream,
                     partial, out);
}

// Round 3
// 65.629 us; speedup vs baseline: 25.0636x; 10.0436x over previous
//
#include <hip/hip_runtime.h>
#include <math.h>

#define BATCH  8192
#define DIM    128
#define NTREES 512
#define UNITS  8

#define RB 64                      // batch rows per block
#define TBL 32                     // trees per block
#define NROWBLK (BATCH/RB)         // 128
#define NTREEBLK (NTREES/TBL)      // 16

typedef __attribute__((ext_vector_type(8))) __bf16 bf16x8;
typedef __attribute__((ext_vector_type(4))) float f32x4;

static __device__ inline unsigned short f2bf(float v) {
  __bf16 h = (__bf16)v;
  return *(unsigned short*)&h;
}

// ---------------------------------------------------------------------------
// prep_w: sort-free sparsemax per (tree,d) fused with temperature, written as
// bf16 into the swizzled LDS image W_img[subtile(16 trees)][slot=tree*8+d][dim]
// with byte swizzle ^((slot&7)<<4).  Slots d=6,7 are zero padding.
// biasPad[t][d] = -thr*exp(-logT).
// ---------------------------------------------------------------------------
__global__ __launch_bounds__(128) void prep_w(
    const float* __restrict__ logits, const float* __restrict__ thr,
    const float* __restrict__ logtemp, unsigned short* __restrict__ Wimg,
    float* __restrict__ biasPad)
{
  int blk = blockIdx.x; int t = blk >> 3; int d = blk & 7; int i = threadIdx.x;
  int slot = ((t & 15) << 3) + d;
  size_t base = ((size_t)(t >> 4)) * 16384 + (size_t)slot * 128;  // ushort units
  int col = ((i * 2) ^ ((slot & 7) << 4)) >> 1;
  if (d >= 6) {
    Wimg[base + col] = 0;
    if (i == 0) biasPad[t * 8 + d] = 0.f;
    return;
  }
  __shared__ float z[128], rc[128], rs[128];
  float zi = logits[((size_t)i * NTREES + t) * 6 + d];
  z[i] = zi;
  __syncthreads();
  float k = 0.f, S = 0.f;
  for (int jj = 0; jj < 128; ++jj) {
    float zj = z[jj];
    if (zj >= zi) { k += 1.f; S += zj; }
  }
  bool sup = (1.f + k * zi) > S;
  rc[i] = sup ? 1.f : 0.f;
  rs[i] = sup ? zi : 0.f;
  __syncthreads();
  for (int off = 64; off > 0; off >>= 1) {
    if (i < off) { rc[i] += rc[i + off]; rs[i] += rs[i + off]; }
    __syncthreads();
  }
  float tau = (rs[0] - 1.f) / rc[0];
  float et = expf(-logtemp[t * 6 + d]);
  Wimg[base + col] = f2bf(fmaxf(zi - tau, 0.f) * et);
  if (i == 0) biasPad[t * 8 + d] = -thr[t * 6 + d] * et;
}

// ---------------------------------------------------------------------------
// prep_x: inputs -> bf16, row-swizzled image Ximg[row][ (col*2)^((row&7)<<4) ]
// ---------------------------------------------------------------------------
__global__ __launch_bounds__(128) void prep_x(
    const float* __restrict__ inputs, unsigned short* __restrict__ Ximg)
{
  int r = blockIdx.x, k = threadIdx.x;
  float v = inputs[(size_t)r * DIM + k];
  int col = ((k * 2) ^ ((r & 7) << 4)) >> 1;
  Ximg[(size_t)r * DIM + col] = f2bf(v);
}

// ---------------------------------------------------------------------------
// prep_r: response -> bf16 B-fragment stream for GEMM2.
// Rb[((pair*4+ks)*64+lane)*8 + j] = B[k=ks*32+(lane>>4)*8+j][u=lane&15]
//   = response[tree=pair*2+(k>=64)][u][leaf=k&63], 0 for u>=8.
// ---------------------------------------------------------------------------
__global__ __launch_bounds__(256) void prep_r(
    const float* __restrict__ resp, unsigned short* __restrict__ Rb)
{
  int idx = blockIdx.x * 256 + threadIdx.x;  // < 524288
  int j = idx & 7;
  int lane = (idx >> 3) & 63;
  int ks = (idx >> 9) & 3;
  int pair = idx >> 11;
  int kg = ks * 32 + ((lane >> 4) << 3) + j;
  int tree = pair * 2 + (kg >> 6);
  int leaf = kg & 63;
  int u = lane & 15;
  float v = (u < 8) ? resp[((size_t)tree * 8 + u) * 64 + leaf] : 0.f;
  Rb[idx] = f2bf(v);
}

// ---------------------------------------------------------------------------
// Main: per block 64 batch rows x 32 trees (2 subtiles of 16 trees).
// 4 waves; wave owns 4 trees/subtile = 2 tree-pairs = 2 GEMM1 M-tiles.
// GEMM1 (swapped): fv[slot][batch] = W(slots x 128dim) @ X^T -> fv in-lane
// for batch col lane&15.  Gates/leaf products in-register; GEMM2 P@R via MFMA
// accumulated over all 8 trees of the wave.
// ---------------------------------------------------------------------------
__global__ __launch_bounds__(256, 3) void odt_main(
    const unsigned short* __restrict__ Ximg, const unsigned short* __restrict__ Wimg,
    const float* __restrict__ biasPad, const unsigned short* __restrict__ Rb,
    float* __restrict__ partial)
{
  __shared__ char pool[50176];
  char* Xl = pool;                       // 16384 B
  char* Wl = pool + 16384;               // 32768 B
  float* biasl = (float*)(pool + 49152); // 1024 B
  float* outred = (float*)(pool + 16384); // aliases Wl after final barrier

  const int tid = threadIdx.x;
  const int lane = tid & 63;
  const int w = tid >> 6;       // wave 0..3
  const int G = lane >> 4;      // 0..3
  const int ln = lane & 15;
  const int bx = blockIdx.x, tb = blockIdx.y;

  // stage X tile (16KB, already swizzled in global)
  {
    const float4* src = (const float4*)(Ximg + (size_t)bx * RB * DIM);
    float4* dst = (float4*)Xl;
    #pragma unroll
    for (int it = 0; it < 4; ++it) dst[tid + it * 256] = src[tid + it * 256];
  }
  // stage bias for the block's 32 trees (256 floats)
  biasl[tid] = biasPad[(size_t)tb * 256 + tid];

  f32x4 out[4];
  #pragma unroll
  for (int nt = 0; nt < 4; ++nt)
    #pragma unroll
    for (int r = 0; r < 4; ++r) out[nt][r] = 0.f;

  for (int sub = 0; sub < 2; ++sub) {
    if (sub) __syncthreads();          // protect Wl from overwrite
    {
      const float4* src = (const float4*)(Wimg + ((size_t)(tb * 2 + sub)) * 16384);
      float4* dst = (float4*)Wl;
      #pragma unroll
      for (int it = 0; it < 8; ++it) dst[tid + it * 256] = src[tid + it * 256];
    }
    __syncthreads();

    // ---- GEMM1: fv[slot][batch], slots = wave's 32 (2 Mtiles of 16) ----
    bf16x8 Afr[2][4];
    #pragma unroll
    for (int p = 0; p < 2; ++p)
      #pragma unroll
      for (int ks = 0; ks < 4; ++ks) {
        int slot = 32 * w + 16 * p + ln;
        int byte = slot * 256 + ((ks * 64 + G * 16) ^ ((slot & 7) << 4));
        Afr[p][ks] = *(const bf16x8*)(Wl + byte);
      }
    f32x4 c1[2][4];
    #pragma unroll
    for (int p = 0; p < 2; ++p)
      #pragma unroll
      for (int nt = 0; nt < 4; ++nt)
        #pragma unroll
        for (int r = 0; r < 4; ++r) c1[p][nt][r] = 0.f;

    #pragma unroll
    for (int nt = 0; nt < 4; ++nt) {
      bf16x8 Bfr[4];
      #pragma unroll
      for (int ks = 0; ks < 4; ++ks) {
        int row = nt * 16 + ln;
        int byte = row * 256 + ((ks * 64 + G * 16) ^ ((row & 7) << 4));
        Bfr[ks] = *(const bf16x8*)(Xl + byte);
      }
      #pragma unroll
      for (int p = 0; p < 2; ++p)
        #pragma unroll
        for (int ks = 0; ks < 4; ++ks)
          c1[p][nt] = __builtin_amdgcn_mfma_f32_16x16x32_bf16(
              Afr[p][ks], Bfr[ks], c1[p][nt], 0, 0, 0);
    }

    // ---- epilogue: gates -> leaf fragments -> GEMM2 ----
    #pragma unroll
    for (int p = 0; p < 2; ++p) {
      int pairg = tb * 16 + sub * 8 + 2 * w + p;
      bf16x8 B2[4];
      #pragma unroll
      for (int ks = 0; ks < 4; ++ks)
        B2[ks] = ((const bf16x8*)Rb)[(size_t)(pairg * 4 + ks) * 64 + lane];
      int treeloc = sub * 16 + 4 * w + 2 * p + (G >> 1);
      float bv[6];
      #pragma unroll
      for (int d = 0; d < 6; ++d) bv[d] = biasl[treeloc * 8 + d];

      #pragma unroll
      for (int nt = 0; nt < 4; ++nt) {
        // merge the two lane-halves so this lane has its tree's 8 fv slots
        float fva[4], fvb[4];
        #pragma unroll
        for (int r = 0; r < 4; ++r) {
          fva[r] = c1[p][nt][r];
          fvb[r] = __shfl_xor(c1[p][nt][r], 16);
        }
        bool hiHalf = (G & 1);
        float fd[6];
        #pragma unroll
        for (int r = 0; r < 4; ++r) fd[r] = hiHalf ? fvb[r] : fva[r];
        fd[4] = hiHalf ? fva[0] : fvb[0];
        fd[5] = hiHalf ? fva[1] : fvb[1];

        // own tree's gates
        float s[6], om[6];
        #pragma unroll
        for (int d = 0; d < 6; ++d) {
          float tl = fd[d] + bv[d];
          float sv = fminf(fmaxf(0.5f + 0.5f * tl, 0.f), 1.f);
          s[d] = sv; om[d] = 1.f - sv;
        }
        // other tree of the pair
        float s2[6], om2[6];
        #pragma unroll
        for (int d = 0; d < 6; ++d) {
          s2[d] = __shfl_xor(s[d], 32);
          om2[d] = 1.f - s2[d];
        }
        bool isOdd = (G >> 1) & 1;
        float sE[6], omE[6], sO[6], omO[6];
        #pragma unroll
        for (int d = 0; d < 6; ++d) {
          sE[d] = isOdd ? s2[d] : s[d];  omE[d] = isOdd ? om2[d] : om[d];
          sO[d] = isOdd ? s[d] : s2[d];  omO[d] = isOdd ? om[d] : om2[d];
        }
        // depth-0..2 subtree products (leaf bit d=0 -> s, bit=1 -> om)
        float p3E[8], p3O[8];
        {
          float q00 = sE[0]*sE[1], q10 = omE[0]*sE[1];
          float q01 = sE[0]*omE[1], q11 = omE[0]*omE[1];
          p3E[0]=q00*sE[2];  p3E[1]=q10*sE[2];  p3E[2]=q01*sE[2];  p3E[3]=q11*sE[2];
          p3E[4]=q00*omE[2]; p3E[5]=q10*omE[2]; p3E[6]=q01*omE[2]; p3E[7]=q11*omE[2];
        }
        {
          float q00 = sO[0]*sO[1], q10 = omO[0]*sO[1];
          float q01 = sO[0]*omO[1], q11 = omO[0]*omO[1];
          p3O[0]=q00*sO[2];  p3O[1]=q10*sO[2];  p3O[2]=q01*sO[2];  p3O[3]=q11*sO[2];
          p3O[4]=q00*omO[2]; p3O[5]=q10*omO[2]; p3O[6]=q01*omO[2]; p3O[7]=q11*omO[2];
        }
        // high-bit commons: bit3=G&1, bit4=(G>>1)&1, bit5=kstep-within-tree
        float cE34 = ((G & 1) ? omE[3] : sE[3]) * ((G & 2) ? omE[4] : sE[4]);
        float cE0 = cE34 * sE[5], cE1 = cE34 * omE[5];
        float cO34 = ((G & 1) ? omO[3] : sO[3]) * ((G & 2) ? omO[4] : sO[4]);
        float cO0 = cO34 * sO[5], cO1 = cO34 * omO[5];

        bf16x8 A0, A1, A2, A3;
        #pragma unroll
        for (int j = 0; j < 8; ++j) {
          A0[j] = (__bf16)(cE0 * p3E[j]);
          A1[j] = (__bf16)(cE1 * p3E[j]);
          A2[j] = (__bf16)(cO0 * p3O[j]);
          A3[j] = (__bf16)(cO1 * p3O[j]);
        }
        out[nt] = __builtin_amdgcn_mfma_f32_16x16x32_bf16(A0, B2[0], out[nt], 0,0,0);
        out[nt] = __builtin_amdgcn_mfma_f32_16x16x32_bf16(A1, B2[1], out[nt], 0,0,0);
        out[nt] = __builtin_amdgcn_mfma_f32_16x16x32_bf16(A2, B2[2], out[nt], 0,0,0);
        out[nt] = __builtin_amdgcn_mfma_f32_16x16x32_bf16(A3, B2[3], out[nt], 0,0,0);
      }
    }
  }

  // ---- cross-wave reduction (outred aliases Wl; all Wl reads are done) ----
  __syncthreads();
  if (ln < 8) {
    #pragma unroll
    for (int nt = 0; nt < 4; ++nt)
      #pragma unroll
      for (int r = 0; r < 4; ++r)
        outred[((size_t)w * 64 + nt * 16 + 4 * G + r) * 8 + ln] = out[nt][r];
  }
  __syncthreads();
  #pragma unroll
  for (int v = 0; v < 2; ++v) {
    int e = tid + v * 256;              // 0..511 = row*8+u
    int row = e >> 3, u = e & 7;
    float sum = outred[(size_t)(0 * 64 + row) * 8 + u]
              + outred[(size_t)(1 * 64 + row) * 8 + u]
              + outred[(size_t)(2 * 64 + row) * 8 + u]
              + outred[(size_t)(3 * 64 + row) * 8 + u];
    partial[((size_t)tb * BATCH + bx * RB + row) * 8 + u] = sum;
  }
}

// ---------------------------------------------------------------------------
// reduce over the 16 tree-blocks, scale by 1/512
// ---------------------------------------------------------------------------
__global__ __launch_bounds__(256) void odt_reduce(
    const float* __restrict__ partial, float* __restrict__ out)
{
  int i = blockIdx.x * 256 + threadIdx.x;   // 0..65535
  float s = 0.f;
  #pragma unroll
  for (int t = 0; t < NTREEBLK; ++t)
    s += partial[(size_t)t * BATCH * UNITS + i];
  out[i] = s * (1.f / NTREES);
}

extern "C" void kernel_launch(void* const* d_in, const int* in_sizes, int n_in,
                              void* d_out, int out_size, void* d_ws, size_t ws_size,
                              hipStream_t stream)
{
  const float* inputs   = (const float*)d_in[0];
  const float* logits   = (const float*)d_in[1];
  const float* thr      = (const float*)d_in[2];
  const float* logtemp  = (const float*)d_in[3];
  const float* response = (const float*)d_in[4];
  float* out = (float*)d_out;

  char* ws = (char*)d_ws;
  unsigned short* Wimg = (unsigned short*)(ws);                 // 1 MB
  unsigned short* Ximg = (unsigned short*)(ws + (1<<20));       // 2 MB
  unsigned short* Rb   = (unsigned short*)(ws + (3<<20));       // 1 MB
  float* biasPad       = (float*)(ws + (4<<20));                // 16 KB
  float* partial       = (float*)(ws + (4<<20) + (1<<14));      // 4 MB

  hipLaunchKernelGGL(prep_w, dim3(NTREES * 8), dim3(128), 0, stream,
                     logits, thr, logtemp, Wimg, biasPad);
  hipLaunchKernelGGL(prep_x, dim3(BATCH), dim3(128), 0, stream, inputs, Ximg);
  hipLaunchKernelGGL(prep_r, dim3(2048), dim3(256), 0, stream, response, Rb);
  hipLaunchKernelGGL(odt_main, dim3(NROWBLK, NTREEBLK), dim3(256), 0, stream,
                     Ximg, Wimg, biasPad, Rb, partial);
  hipLaunchKernelGGL(odt_reduce, dim3(BATCH * UNITS / 256), dim3(256), 0, stream,
                     partial, out);
}